// Round 1
// baseline (453.525 us; speedup 1.0000x reference)
//
#include <hip/hip_runtime.h>

#define NN 10000      // nodes
#define NE 320000     // edges
#define DD 128        // feature dim
#define NH 8          // heads

typedef __attribute__((ext_vector_type(8)))  __bf16        bf16x8;
typedef __attribute__((ext_vector_type(8)))  unsigned short ushort8v;
typedef __attribute__((ext_vector_type(16))) float         f32x16;

__device__ __forceinline__ unsigned short f2b(float f) {
  unsigned int b = __builtin_bit_cast(unsigned int, f);
  b += 0x7FFFu + ((b >> 16) & 1u);          // RNE to bf16
  return (unsigned short)(b >> 16);
}
__device__ __forceinline__ float b2f(unsigned short u) {
  return __builtin_bit_cast(float, (unsigned int)u << 16);
}
__device__ __forceinline__ f32x16 mfma32(bf16x8 a, bf16x8 b, f32x16 c) {
  return __builtin_amdgcn_mfma_f32_32x32x16_bf16(a, b, c, 0, 0, 0);
}

// ---- transpose/convert weights: W1T[n][k]=We1[k][n] (bf16), W2T, WgT (padded 8->32) ----
__global__ __launch_bounds__(256) void prep_weights_k(
    const float* We1, const float* We2, const float* Wg,
    unsigned short* W1T, unsigned short* W2T, unsigned short* WgT)
{
  int idx = blockIdx.x * 256 + threadIdx.x;
  if (idx < 384 * 128) {
    int n = idx / 384, k = idx - n * 384;
    W1T[idx] = f2b(We1[k * 128 + n]);
  } else if (idx < 384 * 128 + 128 * 128) {
    int o = idx - 384 * 128;
    int n = o >> 7, k = o & 127;
    W2T[o] = f2b(We2[k * 128 + n]);
  } else if (idx < 384 * 128 + 128 * 128 + 32 * 128) {
    int o = idx - (384 * 128 + 128 * 128);
    int n = o >> 7, k = o & 127;
    WgT[o] = (n < 8) ? f2b(Wg[k * 8 + n]) : (unsigned short)0;
  }
}

// ---- per-node Q/K/V projections (f32), 4 nodes per 128-thread block ----
__global__ __launch_bounds__(128) void node_proj_k(
    const float* h, const float* Wq, const float* bq,
    const float* Wk, const float* bk, const float* Wv, const float* bv,
    float* Q, float* K, float* V)
{
  __shared__ float hs[4][132];
  int g = threadIdx.x >> 5, la = threadIdx.x & 31;
  int n = blockIdx.x * 4 + g;
  float4 hv = *(const float4*)(h + (size_t)n * DD + la * 4);
  hs[g][la*4+0] = hv.x; hs[g][la*4+1] = hv.y; hs[g][la*4+2] = hv.z; hs[g][la*4+3] = hv.w;
  __syncthreads();
  float4 q = *(const float4*)(bq + la * 4);
  float4 k = *(const float4*)(bk + la * 4);
  float4 v = *(const float4*)(bv + la * 4);
  for (int kk = 0; kk < DD; ++kk) {
    float a = hs[g][kk];
    float4 wq = *(const float4*)(Wq + (size_t)kk * DD + la * 4);
    float4 wk = *(const float4*)(Wk + (size_t)kk * DD + la * 4);
    float4 wv = *(const float4*)(Wv + (size_t)kk * DD + la * 4);
    q.x += a * wq.x; q.y += a * wq.y; q.z += a * wq.z; q.w += a * wq.w;
    k.x += a * wk.x; k.y += a * wk.y; k.z += a * wk.z; k.w += a * wk.w;
    v.x += a * wv.x; v.y += a * wv.y; v.z += a * wv.z; v.w += a * wv.w;
  }
  *(float4*)(Q + (size_t)n * DD + la * 4) = q;
  *(float4*)(K + (size_t)n * DD + la * 4) = k;
  *(float4*)(V + (size_t)n * DD + la * 4) = v;
}

// ---- logitsT[h][e] = qk/4 + bg (gate added later) ----
__global__ __launch_bounds__(256) void qk_k(const int* ei, const float* Q, const float* K,
                                            const float* bg, float* logitsT)
{
  int e  = blockIdx.x * 32 + (threadIdx.x & 31);
  int h8 = threadIdx.x >> 5;
  int s  = ei[e];
  int d2 = ei[NE + e];
  const float4* qr = (const float4*)(Q + (size_t)d2 * DD + h8 * 16);
  const float4* kr = (const float4*)(K + (size_t)s  * DD + h8 * 16);
  float acc = 0.f;
#pragma unroll
  for (int i = 0; i < 4; ++i) {
    float4 a = qr[i], b = kr[i];
    acc += a.x*b.x + a.y*b.y + a.z*b.z + a.w*b.w;
  }
  logitsT[(size_t)h8 * NE + e] = acc * 0.25f + bg[h8];
}

// ---- convert t->bf16 (optional store) + gate via MFMA, add into logitsT ----
__global__ __launch_bounds__(64) void t_gate_k(const float* t_ij, unsigned short* tb,
                                               const unsigned short* WgT, float* logitsT,
                                               int write_tb)
{
  __shared__ unsigned short T[32][136];
  int e0 = blockIdx.x * 32;
  int lane = threadIdx.x;
  const float4* tp = (const float4*)(t_ij + (size_t)e0 * DD);
#pragma unroll
  for (int i = 0; i < 16; ++i) {
    int gi = lane + i * 64;          // 1024 float4 = 32 rows x 128
    float4 v = tp[gi];
    int row = gi >> 5, c4 = gi & 31;
    ushort4 u; u.x = f2b(v.x); u.y = f2b(v.y); u.z = f2b(v.z); u.w = f2b(v.w);
    *(ushort4*)&T[row][c4 * 4] = u;
    if (write_tb) *(ushort4*)(tb + (size_t)(e0 + row) * DD + c4 * 4) = u;
  }
  __syncthreads();
  int la = lane & 31, hi = lane >> 5;
  f32x16 acc{};
  const unsigned short* wp = WgT + (size_t)la * DD + hi * 8;
#pragma unroll
  for (int ks = 0; ks < 8; ++ks) {
    bf16x8 a = *(const bf16x8*)&T[la][ks * 16 + hi * 8];
    bf16x8 b = *(const bf16x8*)(wp + ks * 16);
    acc = mfma32(a, b, acc);
  }
  if (la < 8) {
#pragma unroll
    for (int r = 0; r < 16; ++r) {
      int row = (r & 3) + 8 * (r >> 2) + 4 * hi;
      logitsT[(size_t)la * NE + e0 + row] += acc[r];
    }
  }
}

// ---- global per-head softmax denominator (no max-shift needed: logits are O(10)) ----
__global__ __launch_bounds__(256) void sumexp_part_k(const float* logitsT, float* partial) {
  int hh = blockIdx.y, b = blockIdx.x;
  const float* p = logitsT + (size_t)hh * NE + (size_t)b * 5000;
  float s = 0.f;
  for (int i = threadIdx.x; i < 5000; i += 256) s += expf(p[i]);
  __shared__ float red[256];
  red[threadIdx.x] = s;
  __syncthreads();
  for (int k = 128; k > 0; k >>= 1) {
    if (threadIdx.x < k) red[threadIdx.x] += red[threadIdx.x + k];
    __syncthreads();
  }
  if (threadIdx.x == 0) partial[hh * 64 + b] = red[0];
}

__global__ void sumexp_fin_k(const float* partial, float* rs) {
  int hh = threadIdx.x;
  if (hh < 8) {
    float s = 0.f;
    for (int i = 0; i < 64; ++i) s += partial[hh * 64 + i];
    rs[hh] = 1.0f / s;
  }
}

// ---- CSR build: deg histogram -> exclusive scan -> bucket ----
__global__ __launch_bounds__(256) void hist_k(const int* ei, int* deg) {
  int e = blockIdx.x * 256 + threadIdx.x;
  atomicAdd(&deg[ei[NE + e]], 1);
}

__global__ __launch_bounds__(1024) void scan_k(const int* deg, int* offs) {
  __shared__ int buf[1024];
  __shared__ int carry;
  int tid = threadIdx.x;
  if (tid == 0) carry = 0;
  __syncthreads();
  for (int base = 0; base < NN; base += 1024) {
    int i = base + tid;
    int v = (i < NN) ? deg[i] : 0;
    buf[tid] = v;
    __syncthreads();
    for (int s = 1; s < 1024; s <<= 1) {
      int t = (tid >= s) ? buf[tid - s] : 0;
      __syncthreads();
      buf[tid] += t;
      __syncthreads();
    }
    if (i < NN) offs[i] = carry + buf[tid] - v;  // exclusive
    __syncthreads();
    if (tid == 0) carry += buf[1023];
    __syncthreads();
  }
  if (tid == 0) offs[NN] = carry;
}

__global__ __launch_bounds__(256) void bucket_k(const int* ei, const int* offs,
                                                int* cursor, int* elist) {
  int e = blockIdx.x * 256 + threadIdx.x;
  int d2 = ei[NE + e];
  int p = atomicAdd(&cursor[d2], 1);
  elist[offs[d2] + p] = e;
}

// ---- gather-sum per node: h_agg[n][d] = sum_e alpha[e][d/16] * V[src[e]][d] ----
__global__ __launch_bounds__(128) void aggregate_k(const int* ei, const int* offs, const int* elist,
                                                   const float* logitsT, const float* rs,
                                                   const float* V, float* h_agg)
{
  int n = blockIdx.x, d = threadIdx.x;
  float rsv = rs[d >> 4];
  const size_t hoff = (size_t)(d >> 4) * NE;
  int st = offs[n], en = offs[n + 1];
  float acc = 0.f;
  for (int i = st; i < en; ++i) {
    int e = elist[i];
    int s = ei[e];
    float a = expf(logitsT[hoff + e]) * rsv;
    acc += a * V[(size_t)s * DD + d];
  }
  h_agg[(size_t)n * DD + d] = acc;
}

// ---- h_new = h + h_agg @ Wo + bo  (f32 to d_out, bf16 copy for MLP) ----
__global__ __launch_bounds__(128) void hnew_k(const float* h, const float* h_agg,
                                              const float* Wo, const float* bo,
                                              float* out_h, unsigned short* hnb)
{
  __shared__ float ag[4][132];
  int g = threadIdx.x >> 5, la = threadIdx.x & 31;
  int n = blockIdx.x * 4 + g;
  float4 av = *(const float4*)(h_agg + (size_t)n * DD + la * 4);
  ag[g][la*4+0] = av.x; ag[g][la*4+1] = av.y; ag[g][la*4+2] = av.z; ag[g][la*4+3] = av.w;
  __syncthreads();
  float4 acc = *(const float4*)(bo + la * 4);
  for (int kk = 0; kk < DD; ++kk) {
    float a = ag[g][kk];
    float4 w = *(const float4*)(Wo + (size_t)kk * DD + la * 4);
    acc.x += a * w.x; acc.y += a * w.y; acc.z += a * w.z; acc.w += a * w.w;
  }
  float4 hv = *(const float4*)(h + (size_t)n * DD + la * 4);
  acc.x += hv.x; acc.y += hv.y; acc.z += hv.z; acc.w += hv.w;
  *(float4*)(out_h + (size_t)n * DD + la * 4) = acc;
  ushort4 u; u.x = f2b(acc.x); u.y = f2b(acc.y); u.z = f2b(acc.z); u.w = f2b(acc.w);
  *(ushort4*)(hnb + (size_t)n * DD + la * 4) = u;
}

// ---- edge MLP: t_out = t + silu([hn[src],hn[dst],t] @ We1 + be1) @ We2 + be2 ----
// 64 edges/block, 4 waves, each wave owns 32 output cols, MFMA 32x32x16 bf16.
template <bool TB>
__global__ __launch_bounds__(256) void edge_mlp_k(
    const int* ei, const unsigned short* hnb, const unsigned short* tb, const float* t_ij,
    const unsigned short* W1T, const unsigned short* W2T,
    const float* be1, const float* be2, float* t_out)
{
  __shared__ unsigned short Ah[64][264];   // cols 0..255 = h_src | h_dst (then reused as Y)
  __shared__ unsigned short Tl[64][136];   // t section (kept for epilogue residual)
  __shared__ int sd[128];
  int tid = threadIdx.x;
  int e0 = blockIdx.x * 64;
  if (tid < 128) sd[tid] = (tid < 64) ? ei[e0 + tid] : ei[NE + e0 + tid - 64];
  __syncthreads();
#pragma unroll
  for (int i = 0; i < 8; ++i) {            // 2048 16B chunks for the two h sections
    int c = tid + i * 256;
    int sec = c >> 10;
    int row = (c >> 4) & 63;
    int cc = c & 15;
    int node = sd[sec * 64 + row];
    ushort8v val = *(const ushort8v*)(hnb + (size_t)node * DD + cc * 8);
    *(ushort8v*)&Ah[row][sec * 128 + cc * 8] = val;
  }
  if (TB) {
#pragma unroll
    for (int i = 0; i < 4; ++i) {
      int c = tid + i * 256;
      int row = c >> 4, cc = c & 15;
      *(ushort8v*)&Tl[row][cc * 8] = *(const ushort8v*)(tb + (size_t)(e0 + row) * DD + cc * 8);
    }
  } else {
#pragma unroll
    for (int i = 0; i < 4; ++i) {
      int c = tid + i * 256;
      int row = c >> 4, cc = c & 15;
      const float4* fp = (const float4*)(t_ij + (size_t)(e0 + row) * DD + cc * 8);
      float4 v0 = fp[0], v1 = fp[1];
      ushort4 u0; u0.x=f2b(v0.x); u0.y=f2b(v0.y); u0.z=f2b(v0.z); u0.w=f2b(v0.w);
      ushort4 u1; u1.x=f2b(v1.x); u1.y=f2b(v1.y); u1.z=f2b(v1.z); u1.w=f2b(v1.w);
      *(ushort4*)&Tl[row][cc * 8]     = u0;
      *(ushort4*)&Tl[row][cc * 8 + 4] = u1;
    }
  }
  __syncthreads();
  int lane = tid & 63, wave = tid >> 6;
  int la = lane & 31, hi = lane >> 5;
  int n0 = wave * 32;
  f32x16 acc0{}, acc1{};
  const unsigned short* w1p = W1T + (size_t)(n0 + la) * 384 + hi * 8;
#pragma unroll 4
  for (int ks = 0; ks < 16; ++ks) {        // K 0..255 from Ah
    bf16x8 a0 = *(const bf16x8*)&Ah[la][ks * 16 + hi * 8];
    bf16x8 a1 = *(const bf16x8*)&Ah[la + 32][ks * 16 + hi * 8];
    bf16x8 b  = *(const bf16x8*)(w1p + ks * 16);
    acc0 = mfma32(a0, b, acc0);
    acc1 = mfma32(a1, b, acc1);
  }
#pragma unroll 4
  for (int ks = 0; ks < 8; ++ks) {         // K 256..383 from Tl
    bf16x8 a0 = *(const bf16x8*)&Tl[la][ks * 16 + hi * 8];
    bf16x8 a1 = *(const bf16x8*)&Tl[la + 32][ks * 16 + hi * 8];
    bf16x8 b  = *(const bf16x8*)(w1p + 256 + ks * 16);
    acc0 = mfma32(a0, b, acc0);
    acc1 = mfma32(a1, b, acc1);
  }
  __syncthreads();                         // all Ah reads done; reuse as Y
  unsigned short* Y = &Ah[0][0];           // view [64][136]
  float b1v = be1[n0 + la];
#pragma unroll
  for (int r = 0; r < 16; ++r) {
    int row = (r & 3) + 8 * (r >> 2) + 4 * hi;
    float v0 = acc0[r] + b1v; v0 = v0 / (1.f + expf(-v0));
    Y[row * 136 + n0 + la] = f2b(v0);
    float v1 = acc1[r] + b1v; v1 = v1 / (1.f + expf(-v1));
    Y[(row + 32) * 136 + n0 + la] = f2b(v1);
  }
  __syncthreads();
  f32x16 c0{}, c1{};
  const unsigned short* w2p = W2T + (size_t)(n0 + la) * DD + hi * 8;
#pragma unroll 4
  for (int ks = 0; ks < 8; ++ks) {
    bf16x8 a0 = *(const bf16x8*)&Y[la * 136 + ks * 16 + hi * 8];
    bf16x8 a1 = *(const bf16x8*)&Y[(la + 32) * 136 + ks * 16 + hi * 8];
    bf16x8 b  = *(const bf16x8*)(w2p + ks * 16);
    c0 = mfma32(a0, b, c0);
    c1 = mfma32(a1, b, c1);
  }
  float b2v = be2[n0 + la];
#pragma unroll
  for (int r = 0; r < 16; ++r) {
    int row = (r & 3) + 8 * (r >> 2) + 4 * hi;
    t_out[(size_t)(e0 + row) * DD + n0 + la]      = b2f(Tl[row][n0 + la])      + c0[r] + b2v;
    t_out[(size_t)(e0 + row + 32) * DD + n0 + la] = b2f(Tl[row + 32][n0 + la]) + c1[r] + b2v;
  }
}

extern "C" void kernel_launch(void* const* d_in, const int* in_sizes, int n_in,
                              void* d_out, int out_size, void* d_ws, size_t ws_size,
                              hipStream_t stream)
{
  const int*   ei   = (const int*)d_in[0];
  const float* h    = (const float*)d_in[1];
  const float* t_ij = (const float*)d_in[2];
  const float* Wq = (const float*)d_in[3];
  const float* bq = (const float*)d_in[4];
  const float* Wk = (const float*)d_in[5];
  const float* bk = (const float*)d_in[6];
  const float* Wv = (const float*)d_in[7];
  const float* bv = (const float*)d_in[8];
  const float* Wg = (const float*)d_in[9];
  const float* bg = (const float*)d_in[10];
  const float* Wo = (const float*)d_in[11];
  const float* bo = (const float*)d_in[12];
  const float* We1 = (const float*)d_in[13];
  const float* be1 = (const float*)d_in[14];
  const float* We2 = (const float*)d_in[15];
  const float* be2 = (const float*)d_in[16];

  char* base = (char*)d_ws;
  size_t o = 0;
  auto take = [&](size_t bytes) -> void* {
    void* p = base + o;
    o = (o + bytes + 255) & ~(size_t)255;
    return p;
  };
  float* Q       = (float*)take((size_t)NN * DD * 4);
  float* K       = (float*)take((size_t)NN * DD * 4);
  float* V       = (float*)take((size_t)NN * DD * 4);
  float* logitsT = (float*)take((size_t)NH * NE * 4);
  float* partial = (float*)take(512 * 4);
  float* rs      = (float*)take(256);
  float* h_agg   = (float*)take((size_t)NN * DD * 4);
  // zero region: deg + cursor contiguous
  char* zbase = base + o;
  int* deg    = (int*)zbase;
  int* cursor = (int*)(zbase + (size_t)NN * 4);
  size_t zbytes = (size_t)NN * 4 * 2;
  o = (o + zbytes + 255) & ~(size_t)255;
  int* offs  = (int*)take((size_t)(NN + 1) * 4);
  int* elist = (int*)take((size_t)NE * 4);
  unsigned short* hnb = (unsigned short*)take((size_t)NN * DD * 2);
  unsigned short* W1T = (unsigned short*)take(384 * 128 * 2);
  unsigned short* W2T = (unsigned short*)take(128 * 128 * 2);
  unsigned short* WgT = (unsigned short*)take(32 * 128 * 2);
  unsigned short* tb  = (unsigned short*)take((size_t)NE * DD * 2);
  bool use_tb = (o <= ws_size);   // fall back to re-reading f32 t if ws too small

  float* out_h = (float*)d_out;
  float* t_out = out_h + (size_t)NN * DD;

  hipMemsetAsync(zbase, 0, zbytes, stream);
  prep_weights_k<<<272, 256, 0, stream>>>(We1, We2, Wg, W1T, W2T, WgT);
  node_proj_k<<<NN / 4, 128, 0, stream>>>(h, Wq, bq, Wk, bk, Wv, bv, Q, K, V);
  qk_k<<<NE / 32, 256, 0, stream>>>(ei, Q, K, bg, logitsT);
  t_gate_k<<<NE / 32, 64, 0, stream>>>(t_ij, tb, WgT, logitsT, use_tb ? 1 : 0);
  sumexp_part_k<<<dim3(64, 8), 256, 0, stream>>>(logitsT, partial);
  sumexp_fin_k<<<1, 64, 0, stream>>>(partial, rs);
  hist_k<<<NE / 256, 256, 0, stream>>>(ei, deg);
  scan_k<<<1, 1024, 0, stream>>>(deg, offs);
  bucket_k<<<NE / 256, 256, 0, stream>>>(ei, offs, cursor, elist);
  aggregate_k<<<NN, 128, 0, stream>>>(ei, offs, elist, logitsT, rs, V, h_agg);
  hnew_k<<<NN / 4, 128, 0, stream>>>(h, h_agg, Wo, bo, out_h, hnb);
  if (use_tb)
    edge_mlp_k<true><<<NE / 64, 256, 0, stream>>>(ei, hnb, tb, t_ij, W1T, W2T, be1, be2, t_out);
  else
    edge_mlp_k<false><<<NE / 64, 256, 0, stream>>>(ei, hnb, tb, t_ij, W1T, W2T, be1, be2, t_out);
}